// Round 6
// baseline (709.329 us; speedup 1.0000x reference)
//
#include <hip/hip_runtime.h>

// PairwiseInteract, round 6: R3's transposed split-bf16 32x32x16 MFMA scheme
// (neuron-permuted C->B slot identity, activations never touch LDS), with the
// tile body rewritten as a 12-stage rolling software pipeline: each stage
// issues the NEXT weight-fragment group's ds_read_b128s before the current
// stage's 6-MFMA chain (double-buffered in register groups P/Q/R/S), so LDS
// traffic retires under MFMA execution instead of serializing with it.
// R3 evidence: cyc/tile ~= MFMA(533)+LDS(480)+VALU(200) -- pure pipe-sum
// convoy. Goal here: max() instead of sum.
// L3 accumulator split in two (fAccA/fAccB) -> 2 independent chains; merged
// free in the epilogue. R4 lesson: no forced occupancy bounds; (256,1).

#define NOBJ 1024
#define H 50
#define F 20

using short8 = __attribute__((ext_vector_type(8))) short;
using v16f   = __attribute__((ext_vector_type(16))) float;

#define MFMA(A, B, C) __builtin_amdgcn_mfma_f32_32x32x16_bf16((A), (B), (C), 0, 0, 0)

__device__ __forceinline__ float trunchi(float x) {
    return __uint_as_float(__float_as_uint(x) & 0xFFFF0000u);
}
// dword = hi16(a) in low half | hi16(b) in high half
__device__ __forceinline__ unsigned pkhi(float a, float b) {
    return __builtin_amdgcn_perm(__float_as_uint(b), __float_as_uint(a), 0x07060302u);
}
__device__ __forceinline__ short8 as_s8(uint4 v) {
    union { uint4 u; short8 s; } x; x.u = v; return x.s;
}
// out-neuron at C slot (mt, tile-row l)
__device__ __forceinline__ int nu(int mt, int l) {
    return 16 * (l >> 3) + 8 * ((l >> 2) & 1) + 4 * mt + (l & 3);
}

// pack one m-tile of C output into dwords 2*MT, 2*MT+1 of the B frags
#define PACK_MT(ACC, MT, XH, XL)                                              \
    _Pragma("unroll") for (int f_ = 0; f_ < 4; ++f_) {                        \
        float r0 = fmaxf((ACC)[4 * f_ + 0], 0.f);                             \
        float r1 = fmaxf((ACC)[4 * f_ + 1], 0.f);                             \
        float r2 = fmaxf((ACC)[4 * f_ + 2], 0.f);                             \
        float r3 = fmaxf((ACC)[4 * f_ + 3], 0.f);                             \
        float l0 = r0 - trunchi(r0), l1 = r1 - trunchi(r1);                   \
        float l2 = r2 - trunchi(r2), l3 = r3 - trunchi(r3);                   \
        ((unsigned*)&(XH)[f_])[2 * (MT) + 0] = pkhi(r0, r1);                  \
        ((unsigned*)&(XH)[f_])[2 * (MT) + 1] = pkhi(r2, r3);                  \
        ((unsigned*)&(XL)[f_])[2 * (MT) + 0] = pkhi(l0, l1);                  \
        ((unsigned*)&(XL)[f_])[2 * (MT) + 1] = pkhi(l2, l3);                  \
    }

#define LDSFRAG(id) (*(const short8*)&wfrag[(id) * 64 + lane])

#define LOAD4(I0, I1, I2, I3, V0, V1, V2, V3)                                 \
    V0 = LDSFRAG(I0); V1 = LDSFRAG(I1); V2 = LDSFRAG(I2); V3 = LDSFRAG(I3);
#define LOAD2(I0, I1, V0, V1)                                                 \
    V0 = LDSFRAG(I0); V1 = LDSFRAG(I1);

// hidden-layer k-fragment step: 6 MFMA (3 per m-tile chain)
#define CHAIN0(XH, XL, AH0, AL0, AH1, AL1) {                                  \
    short8 bh = as_s8((XH)[0]), bl = as_s8((XL)[0]);                          \
    a0 = MFMA(AH0, bh, zero16); a1 = MFMA(AH1, bh, zero16);                   \
    a0 = MFMA(AH0, bl, a0);     a1 = MFMA(AH1, bl, a1);                       \
    a0 = MFMA(AL0, bh, a0);     a1 = MFMA(AL1, bh, a1); }
#define CHAINF(FF, XH, XL, AH0, AL0, AH1, AL1) {                              \
    short8 bh = as_s8((XH)[FF]), bl = as_s8((XL)[FF]);                        \
    a0 = MFMA(AH0, bh, a0); a1 = MFMA(AH1, bh, a1);                           \
    a0 = MFMA(AH0, bl, a0); a1 = MFMA(AH1, bl, a1);                           \
    a0 = MFMA(AL0, bh, a0); a1 = MFMA(AL1, bh, a1); }
#define L3STEP(FF, XH, XL, AH, AL, ACC) {                                     \
    short8 bh = as_s8((XH)[FF]), bl = as_s8((XL)[FF]);                        \
    ACC = MFMA(AH, bh, ACC); ACC = MFMA(AH, bl, ACC); ACC = MFMA(AL, bh, ACC); }

__global__ __launch_bounds__(256, 1)
void pair_kernel(const float* __restrict__ obj0, const float* __restrict__ obj1,
                 const float* __restrict__ prev0, const float* __restrict__ prev1,
                 const float* __restrict__ gW0, const float* __restrict__ gb0,
                 const float* __restrict__ gW1, const float* __restrict__ gb1,
                 const float* __restrict__ gW2, const float* __restrict__ gb2,
                 const float* __restrict__ gW3, const float* __restrict__ gb3,
                 float* __restrict__ forces)
{
    // 40 pre-packed A-fragments (L1:0..15, L2:16..31, L3:32..39), 1KB each
    __shared__ uint4 wfrag[40 * 64];

    const int w    = threadIdx.x >> 6;   // wave 0..3
    const int lane = threadIdx.x & 63;
    const int h    = lane >> 5;          // half-wave
    const int l31  = lane & 31;

    const int m = blockIdx.y;            // module
    const int a = m >> 1, c = m & 1;

    const float* actor = (a == 0) ? obj0 : (a == 1) ? obj1 : (a == 2) ? prev0 : prev1;
    const float* actee = (c == 0) ? obj0 : obj1;

    // ---- stage W1/W2/W3 split-bf16 A-fragments into LDS (once per wg) ----
    for (int combo = w; combo < 20; combo += 4) {
        const int layer = (combo < 8) ? 1 : (combo < 16) ? 2 : 3;
        const int rel   = (layer == 1) ? combo : (layer == 2) ? combo - 8 : combo - 16;
        const int mt    = (layer == 3) ? 0 : (rel >> 2);
        const int f     = (layer == 3) ? rel : (rel & 3);
        const float* W; const float* b; int ncols, col;
        if (layer == 1)      { W = gW1 + m * H * H; b = gb1 + m * H; ncols = H; col = nu(mt, l31); }
        else if (layer == 2) { W = gW2 + m * H * H; b = gb2 + m * H; ncols = H; col = nu(mt, l31); }
        else                 { W = gW3 + m * H * F; b = gb3 + m * F; ncols = F; col = l31; }
        unsigned hs[8], ls[8];
#pragma unroll
        for (int j = 0; j < 8; ++j) {
            const int k = 16 * f + 8 * h + j;
            float wv = 0.f;
            if (col < ncols) {
                if (k < H) wv = W[k * ncols + col];
                else if (k == H) wv = b[col];          // bias row
            }
            unsigned uh = __float_as_uint(wv) & 0xFFFF0000u;
            float lof = wv - __uint_as_float(uh);
            hs[j] = uh;
            ls[j] = __float_as_uint(lof) & 0xFFFF0000u;
        }
        uint4 hi, lo;
        hi.x = (hs[0] >> 16) | hs[1]; hi.y = (hs[2] >> 16) | hs[3];
        hi.z = (hs[4] >> 16) | hs[5]; hi.w = (hs[6] >> 16) | hs[7];
        lo.x = (ls[0] >> 16) | ls[1]; lo.y = (ls[2] >> 16) | ls[3];
        lo.z = (ls[4] >> 16) | ls[5]; lo.w = (ls[6] >> 16) | ls[7];
        wfrag[(combo * 2 + 0) * 64 + lane] = hi;
        wfrag[(combo * 2 + 1) * 64 + lane] = lo;
    }

    // ---- W0ext A-fragments in registers (rows: w0a, w0b, b0, 0...) ----
    short8 W0h[2], W0l[2];
    {
        const float* W0p = gW0 + m * 2 * H;
        const float* b0p = gb0 + m * H;
#pragma unroll
        for (int mt = 0; mt < 2; ++mt) {
            const int col = nu(mt, l31);
            float v0 = 0.f, v1 = 0.f, v2 = 0.f;
            if (h == 0 && col < H) { v0 = W0p[col]; v1 = W0p[H + col]; v2 = b0p[col]; }
            float q0 = v0 - trunchi(v0), q1 = v1 - trunchi(v1), q2 = v2 - trunchi(v2);
            uint4 hi, lo;
            hi.x = pkhi(v0, v1); hi.y = pkhi(v2, 0.f); hi.z = 0u; hi.w = 0u;
            lo.x = pkhi(q0, q1); lo.y = pkhi(q2, 0.f); lo.z = 0u; lo.w = 0u;
            W0h[mt] = as_s8(hi); W0l[mt] = as_s8(lo);
        }
    }
    __syncthreads();

    // ---- per-wave work: one actee, one j-half (16 tiles of 32 pairs) ----
    const int i  = blockIdx.x * 2 + (w >> 1);
    const int jh = w & 1;
    const float av  = actee[i];
    const float avl = av - trunchi(av);
    const unsigned inj = (h == 0) ? 0x00003F80u : 0u;   // 1.0bf16 into slot k=50

    const v16f zero16 = (v16f)0.0f;
    v16f fAccA = (v16f)0.0f, fAccB = (v16f)0.0f;

    // rolling fragment-group buffers (4 frags each for hidden, 2 for L3)
    short8 Pa, Pb, Pc, Pd, Qa, Qb, Qc, Qd, Ra, Rb, Rc, Rd, Sa, Sb, Sc, Sd;

    // prologue: preload g0 = L1 f0 (ids 0,1,8,9)
    LOAD4(0, 1, 8, 9, Pa, Pb, Pc, Pd);

#pragma unroll 1
    for (int jt = 0; jt < 16; ++jt) {
        const int jbase = jh * 512 + jt * 32;
        const float xa  = actor[jbase + l31];
        const float xal = xa - trunchi(xa);

        // prefetch g1 = L1 f1 under the L0 chain
        LOAD4(2, 3, 10, 11, Qa, Qb, Qc, Qd);

        // L0 B operand: k-slots (h=0): 0=actor, 1=actee, 2=1.0(bias)
        uint4 b0h4, b0l4;
        b0h4.x = pkhi(xa, av);   b0h4.y = 0x00003F80u; b0h4.z = 0u; b0h4.w = 0u;
        b0l4.x = pkhi(xal, avl); b0l4.y = 0u;          b0l4.z = 0u; b0l4.w = 0u;
        const short8 B0h = as_s8(b0h4), B0l = as_s8(b0l4);

        // ---- L0: 6 MFMA (register weights, 2 chains) ----
        v16f a0, a1;
        a0 = MFMA(W0h[0], B0h, zero16); a1 = MFMA(W0h[1], B0h, zero16);
        a0 = MFMA(W0h[0], B0l, a0);     a1 = MFMA(W0h[1], B0l, a1);
        a0 = MFMA(W0l[0], B0h, a0);     a1 = MFMA(W0l[1], B0h, a1);

        uint4 X1h[4], X1l[4];
        PACK_MT(a0, 0, X1h, X1l); PACK_MT(a1, 1, X1h, X1l);
        X1h[3].y |= inj;

        // ---- L1: 4 stages, each prefetches the next group then 6 MFMA ----
        LOAD4(4, 5, 12, 13, Ra, Rb, Rc, Rd);    // g2 = L1 f2
        CHAIN0(X1h, X1l, Pa, Pb, Pc, Pd);       // uses g0
        LOAD4(6, 7, 14, 15, Sa, Sb, Sc, Sd);    // g3 = L1 f3
        CHAINF(1, X1h, X1l, Qa, Qb, Qc, Qd);    // uses g1
        LOAD4(16, 17, 24, 25, Pa, Pb, Pc, Pd);  // g4 = L2 f0
        CHAINF(2, X1h, X1l, Ra, Rb, Rc, Rd);    // uses g2
        LOAD4(18, 19, 26, 27, Qa, Qb, Qc, Qd);  // g5 = L2 f1
        CHAINF(3, X1h, X1l, Sa, Sb, Sc, Sd);    // uses g3

        uint4 X2h[4], X2l[4];
        PACK_MT(a0, 0, X2h, X2l); PACK_MT(a1, 1, X2h, X2l);
        X2h[3].y |= inj;

        // ---- L2: same rolling pattern ----
        LOAD4(20, 21, 28, 29, Ra, Rb, Rc, Rd);  // g6 = L2 f2
        CHAIN0(X2h, X2l, Pa, Pb, Pc, Pd);       // uses g4
        LOAD4(22, 23, 30, 31, Sa, Sb, Sc, Sd);  // g7 = L2 f3
        CHAINF(1, X2h, X2l, Qa, Qb, Qc, Qd);    // uses g5
        LOAD2(32, 33, Pa, Pb);                  // g8 = L3 f0
        CHAINF(2, X2h, X2l, Ra, Rb, Rc, Rd);    // uses g6
        LOAD2(34, 35, Qa, Qb);                  // g9 = L3 f1
        CHAINF(3, X2h, X2l, Sa, Sb, Sc, Sd);    // uses g7

        uint4 X3h[4], X3l[4];
        PACK_MT(a0, 0, X3h, X3l); PACK_MT(a1, 1, X3h, X3l);
        X3h[3].y |= inj;

        // ---- L3: 12 MFMA into 2 independent accumulator chains ----
        LOAD2(36, 37, Ra, Rb);                  // g10 = L3 f2
        L3STEP(0, X3h, X3l, Pa, Pb, fAccA);     // uses g8
        LOAD2(38, 39, Sa, Sb);                  // g11 = L3 f3
        L3STEP(1, X3h, X3l, Qa, Qb, fAccB);     // uses g9
        LOAD4(0, 1, 8, 9, Pa, Pb, Pc, Pd);      // g0 for next tile
        L3STEP(2, X3h, X3l, Ra, Rb, fAccA);     // uses g10
        L3STEP(3, X3h, X3l, Sa, Sb, fAccB);     // uses g11
    }

    // ---- reduce over pairs (columns) and commit ----
    float* dst = forces + (c * NOBJ + i) * F;
#pragma unroll
    for (int r = 0; r < 16; ++r) {
        float v = fAccA[r] + fAccB[r];
        v += __shfl_xor(v, 1);
        v += __shfl_xor(v, 2);
        v += __shfl_xor(v, 4);
        v += __shfl_xor(v, 8);
        v += __shfl_xor(v, 16);
        const int row = (r & 3) + 8 * (r >> 2) + 4 * h;   // natural L3 out-feature
        if (l31 == 0 && row < F) atomicAdd(dst + row, v);
    }
}

__global__ __launch_bounds__(256)
void apply_kernel(const float* __restrict__ forces,
                  const float* __restrict__ aW0, const float* __restrict__ ab0,
                  const float* __restrict__ aW1, const float* __restrict__ ab1,
                  float* __restrict__ out)
{
    const int t = blockIdx.x * 256 + threadIdx.x;   // 0..2047
    const int c = t >> 10;                          // wave-uniform
    const int i = t & 1023;

    const float* f = forces + (c * NOBJ + i) * F;
    float fin[F];
#pragma unroll
    for (int k = 0; k < F; ++k) fin[k] = f[k];

    const float* __restrict__ w0 = aW0 + c * F * H;   // (20,50)
    const float* __restrict__ b0 = ab0 + c * H;
    const float* __restrict__ w1 = aW1 + c * H;       // (50,1)
    float pred = ab1[c];
#pragma unroll
    for (int o = 0; o < H; ++o) {
        float s = b0[o];
#pragma unroll
        for (int k = 0; k < F; ++k) s = fmaf(fin[k], w0[k * H + o], s);
        pred = fmaf(fmaxf(s, 0.f), w1[o], pred);
    }
    out[t] = pred;
}

extern "C" void kernel_launch(void* const* d_in, const int* in_sizes, int n_in,
                              void* d_out, int out_size, void* d_ws, size_t ws_size,
                              hipStream_t stream) {
    const float* obj0  = (const float*)d_in[0];
    const float* obj1  = (const float*)d_in[1];
    const float* prev0 = (const float*)d_in[2];
    const float* prev1 = (const float*)d_in[3];
    const float* gW0 = (const float*)d_in[4];
    const float* gb0 = (const float*)d_in[5];
    const float* gW1 = (const float*)d_in[6];
    const float* gb1 = (const float*)d_in[7];
    const float* gW2 = (const float*)d_in[8];
    const float* gb2 = (const float*)d_in[9];
    const float* gW3 = (const float*)d_in[10];
    const float* gb3 = (const float*)d_in[11];
    const float* aW0 = (const float*)d_in[12];
    const float* ab0 = (const float*)d_in[13];
    const float* aW1 = (const float*)d_in[14];
    const float* ab1 = (const float*)d_in[15];

    float* forces = (float*)d_ws;   // [2][1024][20] fp32 accumulator
    hipMemsetAsync(forces, 0, 2 * NOBJ * F * sizeof(float), stream);

    dim3 grid(NOBJ / 2, 8);   // i-groups x modules; 4 waves/wg: 2 actees x 2 j-halves
    pair_kernel<<<grid, 256, 0, stream>>>(obj0, obj1, prev0, prev1,
                                          gW0, gb0, gW1, gb1, gW2, gb2, gW3, gb3,
                                          forces);

    apply_kernel<<<8, 256, 0, stream>>>(forces, aW0, ab0, aW1, ab1, (float*)d_out);
}

// Round 10
// 695.467 us; speedup vs baseline: 1.0199x; 1.0199x over previous
//
#include <hip/hip_runtime.h>

// PairwiseInteract, round 10: R3 body (proven 519us runner) with the 8 L3
// weight fragments moved from LDS into per-wave registers:
//   - wfrag shrinks 40KB -> exactly 32KB (tests the LDS-granularity occupancy
//     theory: R3's 40KB/4-wave blocks ran only 2 blocks/CU = 22% occ, and
//     R4's 40KB/8-wave blocks ran 47% -- both consistent with 40KB rounding
//     up to ~64KB per block)
//   - per-tile LDS b128 reads drop 40 -> 32 (L3 frags register-resident)
// Cost: +32 VGPR (~160 total -> 3 waves/SIMD; if >170 it falls back to R3's
// residency, still with 20% less LDS traffic -- bounded downside).
// R4 lesson: never force VGPR below natural use. R6 lesson: no source-level
// pipelining. R7-R9 lesson: __launch_bounds__(512,1) source kills containers
// 3/3 (suspected compile-time blowup) -- abandoned; 256-thread blocks only.

#define NOBJ 1024
#define H 50
#define F 20

using short8 = __attribute__((ext_vector_type(8))) short;
using v16f   = __attribute__((ext_vector_type(16))) float;

#define MFMA(A, B, C) __builtin_amdgcn_mfma_f32_32x32x16_bf16((A), (B), (C), 0, 0, 0)

__device__ __forceinline__ float trunchi(float x) {
    return __uint_as_float(__float_as_uint(x) & 0xFFFF0000u);
}
// dword = hi16(a) in low half | hi16(b) in high half
__device__ __forceinline__ unsigned pkhi(float a, float b) {
    return __builtin_amdgcn_perm(__float_as_uint(b), __float_as_uint(a), 0x07060302u);
}
__device__ __forceinline__ short8 as_s8(uint4 v) {
    union { uint4 u; short8 s; } x; x.u = v; return x.s;
}
// out-neuron at C slot (mt, tile-row l)
__device__ __forceinline__ int nu(int mt, int l) {
    return 16 * (l >> 3) + 8 * ((l >> 2) & 1) + 4 * mt + (l & 3);
}

// pack one m-tile of C output into dwords 2*MT, 2*MT+1 of the B frags
#define PACK_MT(ACC, MT, XH, XL)                                              \
    _Pragma("unroll") for (int f_ = 0; f_ < 4; ++f_) {                        \
        float r0 = fmaxf((ACC)[4 * f_ + 0], 0.f);                             \
        float r1 = fmaxf((ACC)[4 * f_ + 1], 0.f);                             \
        float r2 = fmaxf((ACC)[4 * f_ + 2], 0.f);                             \
        float r3 = fmaxf((ACC)[4 * f_ + 3], 0.f);                             \
        float l0 = r0 - trunchi(r0), l1 = r1 - trunchi(r1);                   \
        float l2 = r2 - trunchi(r2), l3 = r3 - trunchi(r3);                   \
        ((unsigned*)&(XH)[f_])[2 * (MT) + 0] = pkhi(r0, r1);                  \
        ((unsigned*)&(XH)[f_])[2 * (MT) + 1] = pkhi(r2, r3);                  \
        ((unsigned*)&(XL)[f_])[2 * (MT) + 0] = pkhi(l0, l1);                  \
        ((unsigned*)&(XL)[f_])[2 * (MT) + 1] = pkhi(l2, l3);                  \
    }

#define LDSFRAG(id) (*(const short8*)&wfrag[(id) * 64 + lane])

// hidden layer: 2 m-tiles x 4 k-frags x 3 split terms = 24 MFMA
#define LAYER_CHAIN(BASEC, XH, XL, A0, A1)                                    \
    _Pragma("unroll") for (int f_ = 0; f_ < 4; ++f_) {                        \
        short8 ah0 = LDSFRAG(((BASEC) + f_) * 2 + 0);                         \
        short8 al0 = LDSFRAG(((BASEC) + f_) * 2 + 1);                         \
        short8 ah1 = LDSFRAG(((BASEC) + 4 + f_) * 2 + 0);                     \
        short8 al1 = LDSFRAG(((BASEC) + 4 + f_) * 2 + 1);                     \
        short8 bh = as_s8((XH)[f_]), bl = as_s8((XL)[f_]);                    \
        if (f_ == 0) { A0 = MFMA(ah0, bh, zero16); A1 = MFMA(ah1, bh, zero16); } \
        else         { A0 = MFMA(ah0, bh, A0);     A1 = MFMA(ah1, bh, A1); }  \
        A0 = MFMA(ah0, bl, A0); A1 = MFMA(ah1, bl, A1);                       \
        A0 = MFMA(al0, bh, A0); A1 = MFMA(al1, bh, A1);                       \
    }

__global__ __launch_bounds__(256, 1)
void pair_kernel(const float* __restrict__ obj0, const float* __restrict__ obj1,
                 const float* __restrict__ prev0, const float* __restrict__ prev1,
                 const float* __restrict__ gW0, const float* __restrict__ gb0,
                 const float* __restrict__ gW1, const float* __restrict__ gb1,
                 const float* __restrict__ gW2, const float* __restrict__ gb2,
                 const float* __restrict__ gW3, const float* __restrict__ gb3,
                 float* __restrict__ forces)
{
    // 32 pre-packed A-fragments (L1: 0..15, L2: 16..31), 1KB each = 32KB
    __shared__ uint4 wfrag[32 * 64];

    const int w    = threadIdx.x >> 6;   // wave 0..3
    const int lane = threadIdx.x & 63;
    const int h    = lane >> 5;          // half-wave
    const int l31  = lane & 31;

    const int m = blockIdx.y;            // module
    const int a = m >> 1, c = m & 1;

    const float* actor = (a == 0) ? obj0 : (a == 1) ? obj1 : (a == 2) ? prev0 : prev1;
    const float* actee = (c == 0) ? obj0 : obj1;

    // ---- stage W1/W2 split-bf16 A-fragments into LDS (once per wg) ----
    for (int combo = w; combo < 16; combo += 4) {
        const int layer = (combo < 8) ? 1 : 2;
        const int rel   = (layer == 1) ? combo : combo - 8;
        const int mt    = rel >> 2;
        const int f     = rel & 3;
        const float* W = (layer == 1) ? gW1 + m * H * H : gW2 + m * H * H;
        const float* b = (layer == 1) ? gb1 + m * H     : gb2 + m * H;
        const int col  = nu(mt, l31);
        unsigned hs[8], ls[8];
#pragma unroll
        for (int j = 0; j < 8; ++j) {
            const int k = 16 * f + 8 * h + j;
            float wv = 0.f;
            if (col < H) {
                if (k < H) wv = W[k * H + col];
                else if (k == H) wv = b[col];          // bias row
            }
            unsigned uh = __float_as_uint(wv) & 0xFFFF0000u;
            float lof = wv - __uint_as_float(uh);
            hs[j] = uh;
            ls[j] = __float_as_uint(lof) & 0xFFFF0000u;
        }
        uint4 hi, lo;
        hi.x = (hs[0] >> 16) | hs[1]; hi.y = (hs[2] >> 16) | hs[3];
        hi.z = (hs[4] >> 16) | hs[5]; hi.w = (hs[6] >> 16) | hs[7];
        lo.x = (ls[0] >> 16) | ls[1]; lo.y = (ls[2] >> 16) | ls[3];
        lo.z = (ls[4] >> 16) | ls[5]; lo.w = (ls[6] >> 16) | ls[7];
        wfrag[(combo * 2 + 0) * 64 + lane] = hi;
        wfrag[(combo * 2 + 1) * 64 + lane] = lo;
    }

    // ---- W0ext A-fragments in registers (rows: w0a, w0b, b0, 0...) ----
    short8 W0h[2], W0l[2];
    {
        const float* W0p = gW0 + m * 2 * H;
        const float* b0p = gb0 + m * H;
#pragma unroll
        for (int mt = 0; mt < 2; ++mt) {
            const int col = nu(mt, l31);
            float v0 = 0.f, v1 = 0.f, v2 = 0.f;
            if (h == 0 && col < H) { v0 = W0p[col]; v1 = W0p[H + col]; v2 = b0p[col]; }
            float q0 = v0 - trunchi(v0), q1 = v1 - trunchi(v1), q2 = v2 - trunchi(v2);
            uint4 hi, lo;
            hi.x = pkhi(v0, v1); hi.y = pkhi(v2, 0.f); hi.z = 0u; hi.w = 0u;
            lo.x = pkhi(q0, q1); lo.y = pkhi(q2, 0.f); lo.z = 0u; lo.w = 0u;
            W0h[mt] = as_s8(hi); W0l[mt] = as_s8(lo);
        }
    }

    // ---- L3 A-fragments in registers (per-wave copy, was LDS ids 32..39) ----
    short8 B3h[4], B3l[4];
    {
        const float* W3 = gW3 + m * H * F;
        const float* b3 = gb3 + m * F;
#pragma unroll
        for (int f = 0; f < 4; ++f) {
            const int col = l31;                       // n index (< 20 valid)
            unsigned hs[8], ls[8];
#pragma unroll
            for (int j = 0; j < 8; ++j) {
                const int k = 16 * f + 8 * h + j;
                float wv = 0.f;
                if (col < F) {
                    if (k < H) wv = W3[k * F + col];
                    else if (k == H) wv = b3[col];     // bias row
                }
                unsigned uh = __float_as_uint(wv) & 0xFFFF0000u;
                float lof = wv - __uint_as_float(uh);
                hs[j] = uh;
                ls[j] = __float_as_uint(lof) & 0xFFFF0000u;
            }
            uint4 hi, lo;
            hi.x = (hs[0] >> 16) | hs[1]; hi.y = (hs[2] >> 16) | hs[3];
            hi.z = (hs[4] >> 16) | hs[5]; hi.w = (hs[6] >> 16) | hs[7];
            lo.x = (ls[0] >> 16) | ls[1]; lo.y = (ls[2] >> 16) | ls[3];
            lo.z = (ls[4] >> 16) | ls[5]; lo.w = (ls[6] >> 16) | ls[7];
            B3h[f] = as_s8(hi); B3l[f] = as_s8(lo);
        }
    }
    __syncthreads();

    // ---- per-wave work: one actee, one j-half (16 tiles of 32 pairs) ----
    const int i  = blockIdx.x * 2 + (w >> 1);
    const int jh = w & 1;
    const float av  = actee[i];
    const float avl = av - trunchi(av);
    const unsigned inj = (h == 0) ? 0x00003F80u : 0u;   // 1.0bf16 into slot k=50

    const v16f zero16 = (v16f)0.0f;
    v16f fAcc = (v16f)0.0f;

#pragma unroll 1
    for (int jt = 0; jt < 16; ++jt) {
        const int jbase = jh * 512 + jt * 32;
        const float xa  = actor[jbase + l31];
        const float xal = xa - trunchi(xa);

        // L0 B operand: k-slots (h=0): 0=actor, 1=actee, 2=1.0(bias), rest pad
        uint4 b0h4, b0l4;
        b0h4.x = pkhi(xa, av);   b0h4.y = 0x00003F80u; b0h4.z = 0u; b0h4.w = 0u;
        b0l4.x = pkhi(xal, avl); b0l4.y = 0u;          b0l4.z = 0u; b0l4.w = 0u;
        const short8 B0h = as_s8(b0h4), B0l = as_s8(b0l4);

        // ---- L0: 6 MFMA ----
        v16f a0, a1;
        a0 = MFMA(W0h[0], B0h, zero16); a1 = MFMA(W0h[1], B0h, zero16);
        a0 = MFMA(W0h[0], B0l, a0);     a1 = MFMA(W0h[1], B0l, a1);
        a0 = MFMA(W0l[0], B0h, a0);     a1 = MFMA(W0l[1], B0h, a1);

        uint4 X1h[4], X1l[4];
        PACK_MT(a0, 0, X1h, X1l); PACK_MT(a1, 1, X1h, X1l);
        X1h[3].y |= inj;

        // ---- L1: 24 MFMA ----
        LAYER_CHAIN(0, X1h, X1l, a0, a1);
        uint4 X2h[4], X2l[4];
        PACK_MT(a0, 0, X2h, X2l); PACK_MT(a1, 1, X2h, X2l);
        X2h[3].y |= inj;

        // ---- L2: 24 MFMA ----
        LAYER_CHAIN(8, X2h, X2l, a0, a1);
        uint4 X3h[4], X3l[4];
        PACK_MT(a0, 0, X3h, X3l); PACK_MT(a1, 1, X3h, X3l);
        X3h[3].y |= inj;

        // ---- L3: 12 MFMA, register A-frags, accumulate across tiles in C ----
#pragma unroll
        for (int f = 0; f < 4; ++f) {
            short8 bh = as_s8(X3h[f]), bl = as_s8(X3l[f]);
            fAcc = MFMA(B3h[f], bh, fAcc);
            fAcc = MFMA(B3h[f], bl, fAcc);
            fAcc = MFMA(B3l[f], bh, fAcc);
        }
    }

    // ---- reduce over pairs (columns) and commit ----
    float* dst = forces + (c * NOBJ + i) * F;
#pragma unroll
    for (int r = 0; r < 16; ++r) {
        float v = fAcc[r];
        v += __shfl_xor(v, 1);
        v += __shfl_xor(v, 2);
        v += __shfl_xor(v, 4);
        v += __shfl_xor(v, 8);
        v += __shfl_xor(v, 16);
        const int row = (r & 3) + 8 * (r >> 2) + 4 * h;   // natural L3 out-feature
        if (l31 == 0 && row < F) atomicAdd(dst + row, v);
    }
}

__global__ __launch_bounds__(256)
void apply_kernel(const float* __restrict__ forces,
                  const float* __restrict__ aW0, const float* __restrict__ ab0,
                  const float* __restrict__ aW1, const float* __restrict__ ab1,
                  float* __restrict__ out)
{
    const int t = blockIdx.x * 256 + threadIdx.x;   // 0..2047
    const int c = t >> 10;                          // wave-uniform
    const int i = t & 1023;

    const float* f = forces + (c * NOBJ + i) * F;
    float fin[F];
#pragma unroll
    for (int k = 0; k < F; ++k) fin[k] = f[k];

    const float* __restrict__ w0 = aW0 + c * F * H;   // (20,50)
    const float* __restrict__ b0 = ab0 + c * H;
    const float* __restrict__ w1 = aW1 + c * H;       // (50,1)
    float pred = ab1[c];
#pragma unroll
    for (int o = 0; o < H; ++o) {
        float s = b0[o];
#pragma unroll
        for (int k = 0; k < F; ++k) s = fmaf(fin[k], w0[k * H + o], s);
        pred = fmaf(fmaxf(s, 0.f), w1[o], pred);
    }
    out[t] = pred;
}

extern "C" void kernel_launch(void* const* d_in, const int* in_sizes, int n_in,
                              void* d_out, int out_size, void* d_ws, size_t ws_size,
                              hipStream_t stream) {
    const float* obj0  = (const float*)d_in[0];
    const float* obj1  = (const float*)d_in[1];
    const float* prev0 = (const float*)d_in[2];
    const float* prev1 = (const float*)d_in[3];
    const float* gW0 = (const float*)d_in[4];
    const float* gb0 = (const float*)d_in[5];
    const float* gW1 = (const float*)d_in[6];
    const float* gb1 = (const float*)d_in[7];
    const float* gW2 = (const float*)d_in[8];
    const float* gb2 = (const float*)d_in[9];
    const float* gW3 = (const float*)d_in[10];
    const float* gb3 = (const float*)d_in[11];
    const float* aW0 = (const float*)d_in[12];
    const float* ab0 = (const float*)d_in[13];
    const float* aW1 = (const float*)d_in[14];
    const float* ab1 = (const float*)d_in[15];

    float* forces = (float*)d_ws;   // [2][1024][20] fp32 accumulator
    hipMemsetAsync(forces, 0, 2 * NOBJ * F * sizeof(float), stream);

    dim3 grid(NOBJ / 2, 8);   // i-groups x modules; 4 waves/wg: 2 actees x 2 j-halves
    pair_kernel<<<grid, 256, 0, stream>>>(obj0, obj1, prev0, prev1,
                                          gW0, gb0, gW1, gb1, gW2, gb2, gW3, gb3,
                                          forces);

    apply_kernel<<<8, 256, 0, stream>>>(forces, aW0, ab0, aW1, ab1, (float*)d_out);
}

// Round 11
// 550.012 us; speedup vs baseline: 1.2897x; 1.2645x over previous
//
#include <hip/hip_runtime.h>

// PairwiseInteract, round 11: R3's transposed split-bf16 32x32x16 MFMA body
// (proven best: 519us, VGPR 128) in the merged-block geometry: 8 waves per
// 512-thread block sharing ONE 40KB weight-fragment LDS buffer.
// Evidence: R4 (same geometry, launch_bounds(512,4)) measured 47% occupancy —
// the only config ever above 22% — and regressed ONLY because the (,4) bound
// forced VGPR=64 -> 4.8GB scratch spill. R10 falsified the LDS-granularity
// theory (32KB LDS with VGPR 140 -> occupancy FELL to 12%): occupancy is
// register-bracket-bound, and merging blocks is the one lever that raised it.
// Bound here: __launch_bounds__(512, 2) = R4's proven-runnable two-arg form,
// VGPR ceiling 256 >> natural 128 -> no spill possible.
// (R7-R9 used (512,1) and hit 3x container failures — cause unresolved, infra
// outage equally plausible; this two-arg variant is the decisive test.)
// R6 lesson: no source-level pipelining. R4 lesson: never cap below natural.

#define NOBJ 1024
#define H 50
#define F 20

using short8 = __attribute__((ext_vector_type(8))) short;
using v16f   = __attribute__((ext_vector_type(16))) float;

#define MFMA(A, B, C) __builtin_amdgcn_mfma_f32_32x32x16_bf16((A), (B), (C), 0, 0, 0)

__device__ __forceinline__ float trunchi(float x) {
    return __uint_as_float(__float_as_uint(x) & 0xFFFF0000u);
}
// dword = hi16(a) in low half | hi16(b) in high half
__device__ __forceinline__ unsigned pkhi(float a, float b) {
    return __builtin_amdgcn_perm(__float_as_uint(b), __float_as_uint(a), 0x07060302u);
}
__device__ __forceinline__ short8 as_s8(uint4 v) {
    union { uint4 u; short8 s; } x; x.u = v; return x.s;
}
// out-neuron at C slot (mt, tile-row l)
__device__ __forceinline__ int nu(int mt, int l) {
    return 16 * (l >> 3) + 8 * ((l >> 2) & 1) + 4 * mt + (l & 3);
}

// pack one m-tile of C output into dwords 2*MT, 2*MT+1 of the B frags
#define PACK_MT(ACC, MT, XH, XL)                                              \
    _Pragma("unroll") for (int f_ = 0; f_ < 4; ++f_) {                        \
        float r0 = fmaxf((ACC)[4 * f_ + 0], 0.f);                             \
        float r1 = fmaxf((ACC)[4 * f_ + 1], 0.f);                             \
        float r2 = fmaxf((ACC)[4 * f_ + 2], 0.f);                             \
        float r3 = fmaxf((ACC)[4 * f_ + 3], 0.f);                             \
        float l0 = r0 - trunchi(r0), l1 = r1 - trunchi(r1);                   \
        float l2 = r2 - trunchi(r2), l3 = r3 - trunchi(r3);                   \
        ((unsigned*)&(XH)[f_])[2 * (MT) + 0] = pkhi(r0, r1);                  \
        ((unsigned*)&(XH)[f_])[2 * (MT) + 1] = pkhi(r2, r3);                  \
        ((unsigned*)&(XL)[f_])[2 * (MT) + 0] = pkhi(l0, l1);                  \
        ((unsigned*)&(XL)[f_])[2 * (MT) + 1] = pkhi(l2, l3);                  \
    }

#define LDSFRAG(id) (*(const short8*)&wfrag[(id) * 64 + lane])

// hidden layer: 2 m-tiles x 4 k-frags x 3 split terms = 24 MFMA
#define LAYER_CHAIN(BASEC, XH, XL, A0, A1)                                    \
    _Pragma("unroll") for (int f_ = 0; f_ < 4; ++f_) {                        \
        short8 ah0 = LDSFRAG(((BASEC) + f_) * 2 + 0);                         \
        short8 al0 = LDSFRAG(((BASEC) + f_) * 2 + 1);                         \
        short8 ah1 = LDSFRAG(((BASEC) + 4 + f_) * 2 + 0);                     \
        short8 al1 = LDSFRAG(((BASEC) + 4 + f_) * 2 + 1);                     \
        short8 bh = as_s8((XH)[f_]), bl = as_s8((XL)[f_]);                    \
        if (f_ == 0) { A0 = MFMA(ah0, bh, zero16); A1 = MFMA(ah1, bh, zero16); } \
        else         { A0 = MFMA(ah0, bh, A0);     A1 = MFMA(ah1, bh, A1); }  \
        A0 = MFMA(ah0, bl, A0); A1 = MFMA(ah1, bl, A1);                       \
        A0 = MFMA(al0, bh, A0); A1 = MFMA(al1, bh, A1);                       \
    }

__global__ __launch_bounds__(512, 2)
void pair_kernel(const float* __restrict__ obj0, const float* __restrict__ obj1,
                 const float* __restrict__ prev0, const float* __restrict__ prev1,
                 const float* __restrict__ gW0, const float* __restrict__ gb0,
                 const float* __restrict__ gW1, const float* __restrict__ gb1,
                 const float* __restrict__ gW2, const float* __restrict__ gb2,
                 const float* __restrict__ gW3, const float* __restrict__ gb3,
                 float* __restrict__ forces)
{
    // 40 pre-packed A-fragments (L1:0..15, L2:16..31, L3:32..39), 1KB each,
    // shared by all 8 waves of the block
    __shared__ uint4 wfrag[40 * 64];

    const int w    = threadIdx.x >> 6;   // wave 0..7
    const int lane = threadIdx.x & 63;
    const int h    = lane >> 5;          // half-wave
    const int l31  = lane & 31;

    const int m = blockIdx.y;            // module
    const int a = m >> 1, c = m & 1;

    const float* actor = (a == 0) ? obj0 : (a == 1) ? obj1 : (a == 2) ? prev0 : prev1;
    const float* actee = (c == 0) ? obj0 : obj1;

    // ---- stage W1/W2/W3 split-bf16 A-fragments into LDS (once per wg) ----
    for (int combo = w; combo < 20; combo += 8) {
        const int layer = (combo < 8) ? 1 : (combo < 16) ? 2 : 3;
        const int rel   = (layer == 1) ? combo : (layer == 2) ? combo - 8 : combo - 16;
        const int mt    = (layer == 3) ? 0 : (rel >> 2);
        const int f     = (layer == 3) ? rel : (rel & 3);
        const float* W; const float* b; int ncols, col;
        if (layer == 1)      { W = gW1 + m * H * H; b = gb1 + m * H; ncols = H; col = nu(mt, l31); }
        else if (layer == 2) { W = gW2 + m * H * H; b = gb2 + m * H; ncols = H; col = nu(mt, l31); }
        else                 { W = gW3 + m * H * F; b = gb3 + m * F; ncols = F; col = l31; }
        unsigned hs[8], ls[8];
#pragma unroll
        for (int j = 0; j < 8; ++j) {
            const int k = 16 * f + 8 * h + j;
            float wv = 0.f;
            if (col < ncols) {
                if (k < H) wv = W[k * ncols + col];
                else if (k == H) wv = b[col];          // bias row
            }
            unsigned uh = __float_as_uint(wv) & 0xFFFF0000u;
            float lof = wv - __uint_as_float(uh);
            hs[j] = uh;
            ls[j] = __float_as_uint(lof) & 0xFFFF0000u;
        }
        uint4 hi, lo;
        hi.x = (hs[0] >> 16) | hs[1]; hi.y = (hs[2] >> 16) | hs[3];
        hi.z = (hs[4] >> 16) | hs[5]; hi.w = (hs[6] >> 16) | hs[7];
        lo.x = (ls[0] >> 16) | ls[1]; lo.y = (ls[2] >> 16) | ls[3];
        lo.z = (ls[4] >> 16) | ls[5]; lo.w = (ls[6] >> 16) | ls[7];
        wfrag[(combo * 2 + 0) * 64 + lane] = hi;
        wfrag[(combo * 2 + 1) * 64 + lane] = lo;
    }

    // ---- W0ext A-fragments in registers (rows: w0a, w0b, b0, 0...) ----
    short8 W0h[2], W0l[2];
    {
        const float* W0p = gW0 + m * 2 * H;
        const float* b0p = gb0 + m * H;
#pragma unroll
        for (int mt = 0; mt < 2; ++mt) {
            const int col = nu(mt, l31);
            float v0 = 0.f, v1 = 0.f, v2 = 0.f;
            if (h == 0 && col < H) { v0 = W0p[col]; v1 = W0p[H + col]; v2 = b0p[col]; }
            float q0 = v0 - trunchi(v0), q1 = v1 - trunchi(v1), q2 = v2 - trunchi(v2);
            uint4 hi, lo;
            hi.x = pkhi(v0, v1); hi.y = pkhi(v2, 0.f); hi.z = 0u; hi.w = 0u;
            lo.x = pkhi(q0, q1); lo.y = pkhi(q2, 0.f); lo.z = 0u; lo.w = 0u;
            W0h[mt] = as_s8(hi); W0l[mt] = as_s8(lo);
        }
    }
    __syncthreads();

    // ---- per-wave work: one actee, one j-half (16 tiles of 32 pairs) ----
    const int i  = blockIdx.x * 4 + (w >> 1);
    const int jh = w & 1;
    const float av  = actee[i];
    const float avl = av - trunchi(av);
    const unsigned inj = (h == 0) ? 0x00003F80u : 0u;   // 1.0bf16 into slot k=50

    const v16f zero16 = (v16f)0.0f;
    v16f fAcc = (v16f)0.0f;

#pragma unroll 1
    for (int jt = 0; jt < 16; ++jt) {
        const int jbase = jh * 512 + jt * 32;
        const float xa  = actor[jbase + l31];
        const float xal = xa - trunchi(xa);

        // L0 B operand: k-slots (h=0): 0=actor, 1=actee, 2=1.0(bias), rest pad
        uint4 b0h4, b0l4;
        b0h4.x = pkhi(xa, av);   b0h4.y = 0x00003F80u; b0h4.z = 0u; b0h4.w = 0u;
        b0l4.x = pkhi(xal, avl); b0l4.y = 0u;          b0l4.z = 0u; b0l4.w = 0u;
        const short8 B0h = as_s8(b0h4), B0l = as_s8(b0l4);

        // ---- L0: 6 MFMA ----
        v16f a0, a1;
        a0 = MFMA(W0h[0], B0h, zero16); a1 = MFMA(W0h[1], B0h, zero16);
        a0 = MFMA(W0h[0], B0l, a0);     a1 = MFMA(W0h[1], B0l, a1);
        a0 = MFMA(W0l[0], B0h, a0);     a1 = MFMA(W0l[1], B0h, a1);

        uint4 X1h[4], X1l[4];
        PACK_MT(a0, 0, X1h, X1l); PACK_MT(a1, 1, X1h, X1l);
        X1h[3].y |= inj;

        // ---- L1: 24 MFMA ----
        LAYER_CHAIN(0, X1h, X1l, a0, a1);
        uint4 X2h[4], X2l[4];
        PACK_MT(a0, 0, X2h, X2l); PACK_MT(a1, 1, X2h, X2l);
        X2h[3].y |= inj;

        // ---- L2: 24 MFMA ----
        LAYER_CHAIN(8, X2h, X2l, a0, a1);
        uint4 X3h[4], X3l[4];
        PACK_MT(a0, 0, X3h, X3l); PACK_MT(a1, 1, X3h, X3l);
        X3h[3].y |= inj;

        // ---- L3: 12 MFMA, accumulate across tiles in C ----
#pragma unroll
        for (int f = 0; f < 4; ++f) {
            short8 ah = LDSFRAG((16 + f) * 2 + 0);
            short8 al = LDSFRAG((16 + f) * 2 + 1);
            short8 bh = as_s8(X3h[f]), bl = as_s8(X3l[f]);
            fAcc = MFMA(ah, bh, fAcc);
            fAcc = MFMA(ah, bl, fAcc);
            fAcc = MFMA(al, bh, fAcc);
        }
    }

    // ---- reduce over pairs (columns) and commit ----
    float* dst = forces + (c * NOBJ + i) * F;
#pragma unroll
    for (int r = 0; r < 16; ++r) {
        float v = fAcc[r];
        v += __shfl_xor(v, 1);
        v += __shfl_xor(v, 2);
        v += __shfl_xor(v, 4);
        v += __shfl_xor(v, 8);
        v += __shfl_xor(v, 16);
        const int row = (r & 3) + 8 * (r >> 2) + 4 * h;   // natural L3 out-feature
        if (l31 == 0 && row < F) atomicAdd(dst + row, v);
    }
}

__global__ __launch_bounds__(256)
void apply_kernel(const float* __restrict__ forces,
                  const float* __restrict__ aW0, const float* __restrict__ ab0,
                  const float* __restrict__ aW1, const float* __restrict__ ab1,
                  float* __restrict__ out)
{
    const int t = blockIdx.x * 256 + threadIdx.x;   // 0..2047
    const int c = t >> 10;                          // wave-uniform
    const int i = t & 1023;

    const float* f = forces + (c * NOBJ + i) * F;
    float fin[F];
#pragma unroll
    for (int k = 0; k < F; ++k) fin[k] = f[k];

    const float* __restrict__ w0 = aW0 + c * F * H;   // (20,50)
    const float* __restrict__ b0 = ab0 + c * H;
    const float* __restrict__ w1 = aW1 + c * H;       // (50,1)
    float pred = ab1[c];
#pragma unroll
    for (int o = 0; o < H; ++o) {
        float s = b0[o];
#pragma unroll
        for (int k = 0; k < F; ++k) s = fmaf(fin[k], w0[k * H + o], s);
        pred = fmaf(fmaxf(s, 0.f), w1[o], pred);
    }
    out[t] = pred;
}

extern "C" void kernel_launch(void* const* d_in, const int* in_sizes, int n_in,
                              void* d_out, int out_size, void* d_ws, size_t ws_size,
                              hipStream_t stream) {
    const float* obj0  = (const float*)d_in[0];
    const float* obj1  = (const float*)d_in[1];
    const float* prev0 = (const float*)d_in[2];
    const float* prev1 = (const float*)d_in[3];
    const float* gW0 = (const float*)d_in[4];
    const float* gb0 = (const float*)d_in[5];
    const float* gW1 = (const float*)d_in[6];
    const float* gb1 = (const float*)d_in[7];
    const float* gW2 = (const float*)d_in[8];
    const float* gb2 = (const float*)d_in[9];
    const float* gW3 = (const float*)d_in[10];
    const float* gb3 = (const float*)d_in[11];
    const float* aW0 = (const float*)d_in[12];
    const float* ab0 = (const float*)d_in[13];
    const float* aW1 = (const float*)d_in[14];
    const float* ab1 = (const float*)d_in[15];

    float* forces = (float*)d_ws;   // [2][1024][20] fp32 accumulator
    hipMemsetAsync(forces, 0, 2 * NOBJ * F * sizeof(float), stream);

    dim3 grid(NOBJ / 4, 8);   // i-groups x modules; 8 waves/wg: 4 actees x 2 j-halves
    pair_kernel<<<grid, 512, 0, stream>>>(obj0, obj1, prev0, prev1,
                                          gW0, gb0, gW1, gb1, gW2, gb2, gW3, gb3,
                                          forces);

    apply_kernel<<<8, 256, 0, stream>>>(forces, aW0, ab0, aW1, ab1, (float*)d_out);
}